// Round 13
// baseline (604.861 us; speedup 1.0000x reference)
//
#include <hip/hip_runtime.h>

#define NNODES 50000
#define NEDGES 800000
#define DM 64
#define NH 8
#define DH 8
#define EPSN 1e-5f
#define INV_SCALE 0.3535533905932738f   // 1/sqrt(8)
#define SCAN_BLOCKS 200                  // NNODES = 200 * 250 exactly
#define SCAN_CHUNK  250

// ---------------------------------------------------------------------------
// Tiled GEMM (now used only for the embedding).  C = A @ W + bias.
// ---------------------------------------------------------------------------
template<int KA, int KB, int R, bool RELU, bool RES, bool STATS, bool BNRES>
__global__ __launch_bounds__(256, 4) void gemm_k(const float* __restrict__ A,
    const float* __restrict__ W, int woff,
    const float* __restrict__ bias, int boff,
    float* __restrict__ C, float* __restrict__ stats,
    const float* __restrict__ bnstats, const float* __restrict__ bng, int bgoff,
    const float* __restrict__ bnb, int bboff, int Nrows)
{
    constexpr int CG   = KB / 4;
    constexpr int RG   = 256 / CG;
    constexpr int ROWS = RG * R;
    constexpr int APAD = KA + 4;
    constexpr int KAq  = KA / 4;

    __shared__ __align__(16) float sW[KA * KB];
    __shared__ __align__(16) float sA[ROWS * APAD];

    const int tid  = threadIdx.x;
    const int row0 = blockIdx.x * ROWS;

    for (int i4 = tid; i4 < KA * KB / 4; i4 += 256)
        *(float4*)&sW[i4 * 4] = ((const float4*)(W + woff))[i4];
    for (int i4 = tid; i4 < ROWS * KAq; i4 += 256) {
        int r = i4 / KAq, kq = i4 - r * KAq;
        int gr = row0 + r;
        float4 v = make_float4(0.f, 0.f, 0.f, 0.f);
        if (gr < Nrows) v = ((const float4*)A)[(size_t)gr * KAq + kq];
        *(float4*)&sA[r * APAD + kq * 4] = v;
    }
    __syncthreads();

    const int cg = tid % CG, rg = tid / CG;
    const int c0 = cg * 4, r0 = rg * R;

    float4 acc[R];
#pragma unroll
    for (int rr = 0; rr < R; rr++) acc[rr] = make_float4(0.f, 0.f, 0.f, 0.f);

#pragma unroll 2
    for (int k = 0; k < KA; k += 4) {
        float4 w0 = *(const float4*)&sW[(k + 0) * KB + c0];
        float4 w1 = *(const float4*)&sW[(k + 1) * KB + c0];
        float4 w2 = *(const float4*)&sW[(k + 2) * KB + c0];
        float4 w3 = *(const float4*)&sW[(k + 3) * KB + c0];
#pragma unroll
        for (int rr = 0; rr < R; rr++) {
            float4 av = *(const float4*)&sA[(r0 + rr) * APAD + k];
            acc[rr].x += av.x * w0.x + av.y * w1.x + av.z * w2.x + av.w * w3.x;
            acc[rr].y += av.x * w0.y + av.y * w1.y + av.z * w2.y + av.w * w3.y;
            acc[rr].z += av.x * w0.z + av.y * w1.z + av.z * w2.z + av.w * w3.z;
            acc[rr].w += av.x * w0.w + av.y * w1.w + av.z * w2.w + av.w * w3.w;
        }
    }

    float4 bv = make_float4(0.f, 0.f, 0.f, 0.f);
    if (bias) {
        bv.x = bias[boff + c0];     bv.y = bias[boff + c0 + 1];
        bv.z = bias[boff + c0 + 2]; bv.w = bias[boff + c0 + 3];
    }

    float4 scR = make_float4(1.f, 1.f, 1.f, 1.f);
    float4 ofR = make_float4(0.f, 0.f, 0.f, 0.f);
    if (BNRES) {
        const float inv_n = 1.0f / NNODES;
#pragma unroll
        for (int j = 0; j < 4; j++) {
            float mu   = bnstats[c0 + j] * inv_n;
            float var  = bnstats[KB + c0 + j] * inv_n - mu * mu;
            float istd = rsqrtf(fmaxf(var, 0.f) + EPSN);
            float s    = istd * bng[bgoff + c0 + j];
            ((float*)&scR)[j] = s;
            ((float*)&ofR)[j] = bnb[bboff + c0 + j] - mu * s;
        }
    }

    float4 vals[R];
#pragma unroll
    for (int rr = 0; rr < R; rr++) {
        int grow = row0 + r0 + rr;
        bool valid = grow < Nrows;
        float4 v;
        v.x = acc[rr].x + bv.x; v.y = acc[rr].y + bv.y;
        v.z = acc[rr].z + bv.z; v.w = acc[rr].w + bv.w;
        if (RELU) {
            v.x = fmaxf(v.x, 0.f); v.y = fmaxf(v.y, 0.f);
            v.z = fmaxf(v.z, 0.f); v.w = fmaxf(v.w, 0.f);
        }
        if (valid) {
            if (RES) {
                float4 old = *(const float4*)&C[(size_t)grow * KB + c0];
                if (BNRES) {
                    old.x = old.x * scR.x + ofR.x;
                    old.y = old.y * scR.y + ofR.y;
                    old.z = old.z * scR.z + ofR.z;
                    old.w = old.w * scR.w + ofR.w;
                }
                v.x += old.x; v.y += old.y; v.z += old.z; v.w += old.w;
            }
            *(float4*)&C[(size_t)grow * KB + c0] = v;
        } else {
            v = make_float4(0.f, 0.f, 0.f, 0.f);
        }
        vals[rr] = v;
    }

    if (STATS) {
        __syncthreads();
        float4 cs = make_float4(0.f, 0.f, 0.f, 0.f);
#pragma unroll
        for (int rr = 0; rr < R; rr++) {
            cs.x += vals[rr].x; cs.y += vals[rr].y;
            cs.z += vals[rr].z; cs.w += vals[rr].w;
        }
        *(float4*)&sA[rg * KB + c0] = cs;
        __syncthreads();
        if (tid < KB) {
            float s = 0.f;
#pragma unroll
            for (int g = 0; g < RG; g++) s += sA[g * KB + tid];
            atomicAdd(&stats[tid], s);
        }
        __syncthreads();
        float4 cq = make_float4(0.f, 0.f, 0.f, 0.f);
#pragma unroll
        for (int rr = 0; rr < R; rr++) {
            cq.x += vals[rr].x * vals[rr].x; cq.y += vals[rr].y * vals[rr].y;
            cq.z += vals[rr].z * vals[rr].z; cq.w += vals[rr].w * vals[rr].w;
        }
        *(float4*)&sA[rg * KB + c0] = cq;
        __syncthreads();
        if (tid < KB) {
            float s = 0.f;
#pragma unroll
            for (int g = 0; g < RG; g++) s += sA[g * KB + tid];
            atomicAdd(&stats[KB + tid], s);
        }
    }
}

// ---------------------------------------------------------------------------
// Fused QKV: stage H tile once, loop Wq/Wk/Wv through one sW buffer.
// BNIN: fold the previous layer's BN2 affine into the A-staging.
// ---------------------------------------------------------------------------
template<bool BNIN>
__global__ __launch_bounds__(256, 4) void qkv_k(const float* __restrict__ A,
    const float* __restrict__ Wq, const float* __restrict__ Wk,
    const float* __restrict__ Wv, int woff,
    float* __restrict__ Qo, float* __restrict__ Ko, float* __restrict__ Vo,
    const float* __restrict__ bnstats, const float* __restrict__ bng, int bgoff,
    const float* __restrict__ bnb, int bboff, int Nrows)
{
    constexpr int APAD = 68;
    __shared__ __align__(16) float sW[64 * 64];
    __shared__ __align__(16) float sA[64 * APAD];

    const int tid  = threadIdx.x;
    const int row0 = blockIdx.x * 64;

    // staging: kq = tid & 15 is invariant across the loop -> BN consts once
    {
        const int kq = tid & 15, cc = kq * 4;
        float4 sc = make_float4(1.f, 1.f, 1.f, 1.f);
        float4 of = make_float4(0.f, 0.f, 0.f, 0.f);
        if (BNIN) {
            const float inv_n = 1.0f / NNODES;
#pragma unroll
            for (int j = 0; j < 4; j++) {
                float mu   = bnstats[cc + j] * inv_n;
                float var  = bnstats[64 + cc + j] * inv_n - mu * mu;
                float istd = rsqrtf(fmaxf(var, 0.f) + EPSN);
                float s    = istd * bng[bgoff + cc + j];
                ((float*)&sc)[j] = s;
                ((float*)&of)[j] = bnb[bboff + cc + j] - mu * s;
            }
        }
        for (int i4 = tid; i4 < 64 * 16; i4 += 256) {   // 64 rows x 16 f4
            int r = i4 >> 4;
            int gr = row0 + r;
            float4 v = make_float4(0.f, 0.f, 0.f, 0.f);
            if (gr < Nrows) {
                v = ((const float4*)A)[(size_t)gr * 16 + kq];
                if (BNIN) {
                    v.x = v.x * sc.x + of.x; v.y = v.y * sc.y + of.y;
                    v.z = v.z * sc.z + of.z; v.w = v.w * sc.w + of.w;
                }
            }
            *(float4*)&sA[r * APAD + cc] = v;
        }
    }

    const float* Ws[3]   = {Wq, Wk, Wv};
    float*       Outs[3] = {Qo, Ko, Vo};

    const int cg = tid & 15, rg = tid >> 4;
    const int c0 = cg * 4, r0 = rg * 4;

    for (int m = 0; m < 3; m++) {
        __syncthreads();   // protects sW (WAR) and, first pass, sA stage
        for (int i4 = tid; i4 < 1024; i4 += 256)
            *(float4*)&sW[i4 * 4] = ((const float4*)(Ws[m] + woff))[i4];
        __syncthreads();

        float4 acc[4];
#pragma unroll
        for (int rr = 0; rr < 4; rr++) acc[rr] = make_float4(0.f, 0.f, 0.f, 0.f);

#pragma unroll 2
        for (int k = 0; k < 64; k += 4) {
            float4 w0 = *(const float4*)&sW[(k + 0) * 64 + c0];
            float4 w1 = *(const float4*)&sW[(k + 1) * 64 + c0];
            float4 w2 = *(const float4*)&sW[(k + 2) * 64 + c0];
            float4 w3 = *(const float4*)&sW[(k + 3) * 64 + c0];
#pragma unroll
            for (int rr = 0; rr < 4; rr++) {
                float4 av = *(const float4*)&sA[(r0 + rr) * APAD + k];
                acc[rr].x += av.x * w0.x + av.y * w1.x + av.z * w2.x + av.w * w3.x;
                acc[rr].y += av.x * w0.y + av.y * w1.y + av.z * w2.y + av.w * w3.y;
                acc[rr].z += av.x * w0.z + av.y * w1.z + av.z * w2.z + av.w * w3.z;
                acc[rr].w += av.x * w0.w + av.y * w1.w + av.z * w2.w + av.w * w3.w;
            }
        }

#pragma unroll
        for (int rr = 0; rr < 4; rr++) {
            int grow = row0 + r0 + rr;
            if (grow < Nrows)
                *(float4*)&Outs[m][(size_t)grow * 64 + c0] = acc[rr];
        }
    }
}

// ---------------------------------------------------------------------------
// Fused FFN (r19 version — measured best at 62-63 µs; four structural
// alternatives all measured worse. Do not modify.)
// ---------------------------------------------------------------------------
__global__ __launch_bounds__(256, 2) void ffn_k(float* __restrict__ H,
    const float* __restrict__ W1, int w1off,
    const float* __restrict__ b1, int b1off,
    const float* __restrict__ W2, int w2off,
    const float* __restrict__ b2, int b2off,
    const float* __restrict__ bnstats,
    const float* __restrict__ bng, int bgoff,
    const float* __restrict__ bnb, int bboff,
    float* __restrict__ stats2, int Nrows)
{
    constexpr int APAD = 68, FPAD = 132;
    __shared__ __align__(16) float sW[128 * 64];   // W1 (64x128) then W2 (128x64)
    __shared__ __align__(16) float sA[32 * APAD];  // BN1(H) rows
    __shared__ __align__(16) float sF[32 * FPAD];  // relu hidden

    const int tid  = threadIdx.x;
    const int row0 = blockIdx.x * 32;

    // stage W1
    for (int i4 = tid; i4 < 2048; i4 += 256)
        *(float4*)&sW[i4 * 4] = ((const float4*)(W1 + w1off))[i4];

    // stage A with BN1 fold (kq = tid & 15 invariant)
    {
        const int kq = tid & 15, cc = kq * 4;
        const float inv_n = 1.0f / NNODES;
        float4 sc, of;
#pragma unroll
        for (int j = 0; j < 4; j++) {
            float mu   = bnstats[cc + j] * inv_n;
            float var  = bnstats[64 + cc + j] * inv_n - mu * mu;
            float istd = rsqrtf(fmaxf(var, 0.f) + EPSN);
            float s    = istd * bng[bgoff + cc + j];
            ((float*)&sc)[j] = s;
            ((float*)&of)[j] = bnb[bboff + cc + j] - mu * s;
        }
        for (int i4 = tid; i4 < 512; i4 += 256) {   // 32 rows x 16 f4
            int r = i4 >> 4;
            int gr = row0 + r;
            float4 v = make_float4(0.f, 0.f, 0.f, 0.f);
            if (gr < Nrows) {
                v = ((const float4*)H)[(size_t)gr * 16 + kq];
                v.x = v.x * sc.x + of.x; v.y = v.y * sc.y + of.y;
                v.z = v.z * sc.z + of.z; v.w = v.w * sc.w + of.w;
            }
            *(float4*)&sA[r * APAD + cc] = v;
        }
    }
    __syncthreads();

    // phase 1: F = relu(A @ W1 + b1)   (32 x 128), 4 rows x 4 cols / thread
    {
        const int cg = tid & 31, rg = tid >> 5;
        const int c0 = cg * 4, r0 = rg * 4;
        float4 acc[4];
#pragma unroll
        for (int rr = 0; rr < 4; rr++) acc[rr] = make_float4(0.f, 0.f, 0.f, 0.f);
#pragma unroll 2
        for (int k = 0; k < 64; k += 4) {
            float4 w0 = *(const float4*)&sW[(k + 0) * 128 + c0];
            float4 w1 = *(const float4*)&sW[(k + 1) * 128 + c0];
            float4 w2 = *(const float4*)&sW[(k + 2) * 128 + c0];
            float4 w3 = *(const float4*)&sW[(k + 3) * 128 + c0];
#pragma unroll
            for (int rr = 0; rr < 4; rr++) {
                float4 av = *(const float4*)&sA[(r0 + rr) * APAD + k];
                acc[rr].x += av.x * w0.x + av.y * w1.x + av.z * w2.x + av.w * w3.x;
                acc[rr].y += av.x * w0.y + av.y * w1.y + av.z * w2.y + av.w * w3.y;
                acc[rr].z += av.x * w0.z + av.y * w1.z + av.z * w2.z + av.w * w3.z;
                acc[rr].w += av.x * w0.w + av.y * w1.w + av.z * w2.w + av.w * w3.w;
            }
        }
        float4 bb;
        bb.x = b1[b1off + c0];     bb.y = b1[b1off + c0 + 1];
        bb.z = b1[b1off + c0 + 2]; bb.w = b1[b1off + c0 + 3];
#pragma unroll
        for (int rr = 0; rr < 4; rr++) {
            float4 v;
            v.x = fmaxf(acc[rr].x + bb.x, 0.f);
            v.y = fmaxf(acc[rr].y + bb.y, 0.f);
            v.z = fmaxf(acc[rr].z + bb.z, 0.f);
            v.w = fmaxf(acc[rr].w + bb.w, 0.f);
            *(float4*)&sF[(r0 + rr) * FPAD + c0] = v;
        }
    }
    __syncthreads();

    // stage W2 (reuse sW)
    for (int i4 = tid; i4 < 2048; i4 += 256)
        *(float4*)&sW[i4 * 4] = ((const float4*)(W2 + w2off))[i4];
    __syncthreads();

    // phase 2: out = F @ W2 + b2 + BN1residual (from sA)   2 rows x 4 cols
    const int cg = tid & 15, rg = tid >> 4;
    const int c0 = cg * 4, r0 = rg * 2;
    float4 acc[2];
#pragma unroll
    for (int rr = 0; rr < 2; rr++) acc[rr] = make_float4(0.f, 0.f, 0.f, 0.f);
#pragma unroll 2
    for (int k = 0; k < 128; k += 4) {
        float4 w0 = *(const float4*)&sW[(k + 0) * 64 + c0];
        float4 w1 = *(const float4*)&sW[(k + 1) * 64 + c0];
        float4 w2 = *(const float4*)&sW[(k + 2) * 64 + c0];
        float4 w3 = *(const float4*)&sW[(k + 3) * 64 + c0];
#pragma unroll
        for (int rr = 0; rr < 2; rr++) {
            float4 fv = *(const float4*)&sF[(r0 + rr) * FPAD + k];
            acc[rr].x += fv.x * w0.x + fv.y * w1.x + fv.z * w2.x + fv.w * w3.x;
            acc[rr].y += fv.x * w0.y + fv.y * w1.y + fv.z * w2.y + fv.w * w3.y;
            acc[rr].z += fv.x * w0.z + fv.y * w1.z + fv.z * w2.z + fv.w * w3.z;
            acc[rr].w += fv.x * w0.w + fv.y * w1.w + fv.z * w2.w + fv.w * w3.w;
        }
    }
    float4 bb;
    bb.x = b2[b2off + c0];     bb.y = b2[b2off + c0 + 1];
    bb.z = b2[b2off + c0 + 2]; bb.w = b2[b2off + c0 + 3];

    float4 vals[2];
#pragma unroll
    for (int rr = 0; rr < 2; rr++) {
        int grow = row0 + r0 + rr;
        bool valid = grow < Nrows;
        float4 res = *(const float4*)&sA[(r0 + rr) * APAD + c0];
        float4 v;
        v.x = acc[rr].x + bb.x + res.x;
        v.y = acc[rr].y + bb.y + res.y;
        v.z = acc[rr].z + bb.z + res.z;
        v.w = acc[rr].w + bb.w + res.w;
        if (valid) {
            *(float4*)&H[(size_t)grow * 64 + c0] = v;
        } else {
            v = make_float4(0.f, 0.f, 0.f, 0.f);
        }
        vals[rr] = v;
    }

    // stats2: sums then sumsq (scratch reuses sA; barrier-protected)
    __syncthreads();
    float4 cs;
    cs.x = vals[0].x + vals[1].x; cs.y = vals[0].y + vals[1].y;
    cs.z = vals[0].z + vals[1].z; cs.w = vals[0].w + vals[1].w;
    *(float4*)&sA[rg * 64 + c0] = cs;
    __syncthreads();
    if (tid < 64) {
        float s = 0.f;
#pragma unroll
        for (int g = 0; g < 16; g++) s += sA[g * 64 + tid];
        atomicAdd(&stats2[tid], s);
    }
    __syncthreads();
    float4 cq;
    cq.x = vals[0].x * vals[0].x + vals[1].x * vals[1].x;
    cq.y = vals[0].y * vals[0].y + vals[1].y * vals[1].y;
    cq.z = vals[0].z * vals[0].z + vals[1].z * vals[1].z;
    cq.w = vals[0].w * vals[0].w + vals[1].w * vals[1].w;
    *(float4*)&sA[rg * 64 + c0] = cq;
    __syncthreads();
    if (tid < 64) {
        float s = 0.f;
#pragma unroll
        for (int g = 0; g < 16; g++) s += sA[g * 64 + tid];
        atomicAdd(&stats2[64 + tid], s);
    }
}

// bn_apply derives mu/istd from raw sums (final output only)
__global__ __launch_bounds__(256) void bn_apply(const float* __restrict__ Hin,
    float* __restrict__ Hout, const float* __restrict__ stats,
    const float* __restrict__ g, int goff, const float* __restrict__ b, int boff)
{
    int i = blockIdx.x * 256 + threadIdx.x;
    if (i >= NNODES * DM) return;
    int c = i & 63;
    float mu  = stats[c] * (1.0f / NNODES);
    float var = stats[64 + c] * (1.0f / NNODES) - mu * mu;   // biased (jnp.var)
    float istd = rsqrtf(fmaxf(var, 0.0f) + EPSN);
    Hout[i] = (Hin[i] - mu) * istd * g[goff + c] + b[boff + c];
}

// ---------------------------------------------------------------------------
// CSR by dst: count -> hierarchical 3-phase scan -> fill.
// ---------------------------------------------------------------------------
__global__ __launch_bounds__(256) void zero_int_k(int* __restrict__ p, int n)
{
    int i = blockIdx.x * 256 + threadIdx.x;
    if (i < n) p[i] = 0;
}

__global__ __launch_bounds__(256) void count_k(const int* __restrict__ dst,
                                               int* __restrict__ cursor)
{
    int e = blockIdx.x * 256 + threadIdx.x;
    if (e < NEDGES) atomicAdd(&cursor[dst[e]], 1);
}

__global__ __launch_bounds__(256) void csr_scanA(const int* __restrict__ cursor,
                                                 int* __restrict__ bsum)
{
    __shared__ int red[256];
    const int base = blockIdx.x * SCAN_CHUNK;
    int s = 0;
    for (int i = threadIdx.x; i < SCAN_CHUNK; i += 256) s += cursor[base + i];
    red[threadIdx.x] = s;
    __syncthreads();
    for (int o = 128; o > 0; o >>= 1) {
        if (threadIdx.x < o) red[threadIdx.x] += red[threadIdx.x + o];
        __syncthreads();
    }
    if (threadIdx.x == 0) bsum[blockIdx.x] = red[0];
}

__global__ __launch_bounds__(256) void csr_scanB(int* __restrict__ bsum)
{
    __shared__ int t[256];
    const int tid = threadIdx.x;
    int v = (tid < SCAN_BLOCKS) ? bsum[tid] : 0;
    t[tid] = v;
    __syncthreads();
    for (int off = 1; off < 256; off <<= 1) {
        int x = (tid >= off) ? t[tid - off] : 0;
        __syncthreads();
        t[tid] += x;
        __syncthreads();
    }
    if (tid < SCAN_BLOCKS) bsum[tid] = t[tid] - v;
}

__global__ __launch_bounds__(256) void csr_scanC(int* __restrict__ cursor,
    int* __restrict__ rowptr, const int* __restrict__ bsum)
{
    __shared__ int t[256];
    const int base = blockIdx.x * SCAN_CHUNK;
    const int tid  = threadIdx.x;
    int deg = (tid < SCAN_CHUNK) ? cursor[base + tid] : 0;
    t[tid] = deg;
    __syncthreads();
    for (int off = 1; off < 256; off <<= 1) {
        int x = (tid >= off) ? t[tid - off] : 0;
        __syncthreads();
        t[tid] += x;
        __syncthreads();
    }
    int excl = bsum[blockIdx.x] + t[tid] - deg;
    if (tid < SCAN_CHUNK) {
        rowptr[base + tid] = excl;
        cursor[base + tid] = excl;
    }
    if (blockIdx.x == 0 && tid == 0) rowptr[NNODES] = NEDGES;
}

__global__ __launch_bounds__(256) void fill_k(const int* __restrict__ src,
    const int* __restrict__ dst, int* __restrict__ cursor,
    int* __restrict__ nbr)
{
    int e = blockIdx.x * 256 + threadIdx.x;
    if (e >= NEDGES) return;
    int pos = atomicAdd(&cursor[dst[e]], 1);
    nbr[pos] = src[e];
}

// ---------------------------------------------------------------------------
// Fused attention + Wo projection + residual + BN1 stats (r27).
// Gather/softmax math is r18's verbatim (lane-per-(edge,head), zero
// cross-wave deps).  After the butterfly every lane of the wave holds the
// full output row; one scattered LDS write orders it, then a lane-per-col
// 64x64 matvec vs block-staged sWo finishes:
//   H[d] = U[d] @ Wo + bo + BNres(H[d])   ;   statsA += sums/sumsq
// Removes the Wo gemm dispatch + U's 25.6 MB round trip per layer.
// Same-wave LDS RAW needs no barrier (r22-verified).  16 dst/block.
// ---------------------------------------------------------------------------
template<bool BNRES>
__global__ __launch_bounds__(256) void attn_wo_k(const float* __restrict__ Q,
    const float* __restrict__ K, const float* __restrict__ V,
    const int* __restrict__ rowptr, const int* __restrict__ nbr,
    const float* __restrict__ Wo, int woff,
    const float* __restrict__ bo, int boff,
    float* __restrict__ H, float* __restrict__ statsA,
    const float* __restrict__ bnstats,
    const float* __restrict__ bng, int bgoff,
    const float* __restrict__ bnb, int bboff)
{
    __shared__ __align__(16) float sWo[64 * 64];     // 16 KB, row-major [k][c]
    __shared__ __align__(16) float sU[4][64];        // per-wave U row
    __shared__ __align__(16) float sR[4 * 64];       // stats scratch

    const int tid = threadIdx.x;
    const int w   = tid >> 6;
    const int l   = tid & 63;
    const int el  = l >> 3;           // edge slot 0..7
    const int h   = l & 7;            // head

    // stage Wo once per block
    for (int i4 = tid; i4 < 1024; i4 += 256)
        *(float4*)&sWo[i4 * 4] = ((const float4*)(Wo + woff))[i4];
    __syncthreads();

    // per-lane (col = l) epilogue constants
    float scp = 1.f, ofp = 0.f;
    if (BNRES) {
        const float inv_n = 1.0f / NNODES;
        float mu   = bnstats[l] * inv_n;
        float var  = bnstats[64 + l] * inv_n - mu * mu;
        float istd = rsqrtf(fmaxf(var, 0.f) + EPSN);
        scp = istd * bng[bgoff + l];
        ofp = bnb[bboff + l] - mu * scp;
    }
    const float boc = bo[boff + l];

    float csum = 0.f, cqsum = 0.f;
    const int d0 = blockIdx.x * 16 + w * 4;   // 3125 * 16 = 50000 exactly

    for (int t = 0; t < 4; t++) {
        const int d = d0 + t;
        const int e0 = rowptr[d], e1 = rowptr[d + 1];
        const int deg = e1 - e0;

        // ---- gather + online softmax (r18 math, unchanged) ----
        float outv = 0.f;
        if (deg > 0) {
            const float4* qp = (const float4*)(Q + (size_t)d * DM + h * DH);
            const float4 q0 = qp[0], q1 = qp[1];

            float m = 0.0f, S = 0.0f;
            float u[8] = {0.f, 0.f, 0.f, 0.f, 0.f, 0.f, 0.f, 0.f};

            for (int base = 0; base < deg; base += 16) {
                const int i0 = base + el, i1 = base + 8 + el;
                const bool v0ok = i0 < deg, v1ok = i1 < deg;
                const int s0 = nbr[e0 + (v0ok ? i0 : 0)];
                const int s1 = nbr[e0 + (v1ok ? i1 : 0)];

                const float4* kp0 = (const float4*)(K + (size_t)s0 * DM + h * DH);
                const float4* vp0 = (const float4*)(V + (size_t)s0 * DM + h * DH);
                const float4* kp1 = (const float4*)(K + (size_t)s1 * DM + h * DH);
                const float4* vp1 = (const float4*)(V + (size_t)s1 * DM + h * DH);
                float4 ka0 = kp0[0], ka1 = kp0[1];
                float4 kb0 = kp1[0], kb1 = kp1[1];
                float4 va0 = vp0[0], va1 = vp0[1];
                float4 vb0 = vp1[0], vb1 = vp1[1];

                float dd0 = ka0.x * q0.x + ka0.y * q0.y + ka0.z * q0.z + ka0.w * q0.w
                          + ka1.x * q1.x + ka1.y * q1.y + ka1.z * q1.z + ka1.w * q1.w;
                float dd1 = kb0.x * q0.x + kb0.y * q0.y + kb0.z * q0.z + kb0.w * q0.w
                          + kb1.x * q1.x + kb1.y * q1.y + kb1.z * q1.z + kb1.w * q1.w;

                float ev0 = __expf(fminf(fmaxf(dd0 * INV_SCALE, -10.f), 10.f));
                float ev1 = __expf(fminf(fmaxf(dd1 * INV_SCALE, -10.f), 10.f));
                if (!v0ok) ev0 = 0.f;
                if (!v1ok) ev1 = 0.f;

                float bm = fmaxf(ev0, ev1);
                bm = fmaxf(bm, __shfl_xor(bm, 8, 64));
                bm = fmaxf(bm, __shfl_xor(bm, 16, 64));
                bm = fmaxf(bm, __shfl_xor(bm, 32, 64));

                const float mn = fmaxf(m, bm);
                const float r  = __expf(m - mn);    // == 1.0 when mn == m
                const float w0 = v0ok ? __expf(ev0 - mn) : 0.f;
                const float w1 = v1ok ? __expf(ev1 - mn) : 0.f;

                S = S * r + w0 + w1;
                u[0] = u[0] * r + w0 * va0.x + w1 * vb0.x;
                u[1] = u[1] * r + w0 * va0.y + w1 * vb0.y;
                u[2] = u[2] * r + w0 * va0.z + w1 * vb0.z;
                u[3] = u[3] * r + w0 * va0.w + w1 * vb0.w;
                u[4] = u[4] * r + w0 * va1.x + w1 * vb1.x;
                u[5] = u[5] * r + w0 * va1.y + w1 * vb1.y;
                u[6] = u[6] * r + w0 * va1.z + w1 * vb1.z;
                u[7] = u[7] * r + w0 * va1.w + w1 * vb1.w;
                m = mn;
            }

#pragma unroll
            for (int off = 8; off <= 32; off <<= 1) {
                S += __shfl_xor(S, off, 64);
#pragma unroll
                for (int j = 0; j < 8; j++) u[j] += __shfl_xor(u[j], off, 64);
            }
            outv = (S > 0.f) ? u[el] / S : 0.f;
        }

        // row element (h, el) = index h*8+el ; wave-private, in-order DS pipe
        sU[w][h * 8 + el] = outv;

        // ---- matvec: lane l computes output col l ----
        float acc = 0.f;
#pragma unroll
        for (int k4 = 0; k4 < 16; k4++) {
            float4 uu = *(const float4*)&sU[w][k4 * 4];       // broadcast
            acc += uu.x * sWo[(k4 * 4 + 0) * 64 + l];
            acc += uu.y * sWo[(k4 * 4 + 1) * 64 + l];
            acc += uu.z * sWo[(k4 * 4 + 2) * 64 + l];
            acc += uu.w * sWo[(k4 * 4 + 3) * 64 + l];
        }

        float res = H[(size_t)d * DM + l];
        if (BNRES) res = res * scp + ofp;
        float v = acc + boc + res;
        H[(size_t)d * DM + l] = v;
        csum  += v;
        cqsum += v * v;
    }

    // ---- BN1 stats: block-reduce over the 4 waves, one atomic per col ----
    sR[w * 64 + l] = csum;
    __syncthreads();
    if (tid < 64) {
        float s = sR[tid] + sR[64 + tid] + sR[128 + tid] + sR[192 + tid];
        atomicAdd(&statsA[tid], s);
    }
    __syncthreads();
    sR[w * 64 + l] = cqsum;
    __syncthreads();
    if (tid < 64) {
        float s = sR[tid] + sR[64 + tid] + sR[128 + tid] + sR[192 + tid];
        atomicAdd(&statsA[64 + tid], s);
    }
}

__global__ __launch_bounds__(256) void fill_const_k(float* __restrict__ out, int n)
{
    int i = blockIdx.x * 256 + threadIdx.x;
    if (i < n) out[i] = 100.0f;
}

// ---------------------------------------------------------------------------
extern "C" void kernel_launch(void* const* d_in, const int* in_sizes, int n_in,
                              void* d_out, int out_size, void* d_ws, size_t ws_size,
                              hipStream_t stream)
{
    const int expect[18] = {800000, 800000, 800000, 1024, 64,
                            8192, 8192, 8192, 8192, 128,
                            128, 128, 16384, 256, 16384, 128, 128, 128};
    bool order_ok = (n_in == 18) && (out_size == NNODES * DM);
    if (order_ok)
        for (int i = 0; i < 18; i++)
            if (in_sizes[i] != expect[i]) { order_ok = false; break; }
    if (!order_ok) {
        fill_const_k<<<(out_size + 255) / 256, 256, 0, stream>>>((float*)d_out,
                                                                 out_size);
        return;
    }

    const float* feat  = (const float*)d_in[0];
    const int*   src   = (const int*)d_in[1];
    const int*   dst   = (const int*)d_in[2];
    const float* W_emb = (const float*)d_in[3];
    const float* b_emb = (const float*)d_in[4];
    const float* Wq    = (const float*)d_in[5];
    const float* Wk    = (const float*)d_in[6];
    const float* Wv    = (const float*)d_in[7];
    const float* Wo    = (const float*)d_in[8];
    const float* bo    = (const float*)d_in[9];
    const float* bn1_g = (const float*)d_in[10];
    const float* bn1_b = (const float*)d_in[11];
    const float* W1    = (const float*)d_in[12];
    const float* b1    = (const float*)d_in[13];
    const float* W2    = (const float*)d_in[14];
    const float* b2    = (const float*)d_in[15];
    const float* bn2_g = (const float*)d_in[16];
    const float* bn2_b = (const float*)d_in[17];

    const size_t ND = (size_t)NNODES * DM;
    float* ws     = (float*)d_ws;
    float* Hb     = ws;
    float* Qb     = Hb + ND;
    float* Kb     = Qb + ND;
    float* Vb     = Kb + ND;
    float* Ub     = Vb + ND;                        // unused (kept for layout)
    float* stats  = Ub + ND;                        // 256 floats
    int*   rowptr = (int*)(stats + 256);            // N+1
    int*   cursor = rowptr + (NNODES + 1);          // N
    int*   bsum   = cursor + NNODES;                // 200
    int*   nbr    = bsum + SCAN_BLOCKS;             // E

    float* statsA = stats;         // BN1 (attn_wo output) sums/sumsq
    float* statsB = stats + 128;   // BN2 (FFN output) sums/sumsq

    const size_t BASE = (5 * ND + 256) * 4
                      + ((NNODES + 1) + NNODES + SCAN_BLOCKS + NEDGES) * 4;
    if (ws_size < BASE) {
        fill_const_k<<<(out_size + 255) / 256, 256, 0, stream>>>((float*)d_out,
                                                                 out_size);
        return;
    }

    const int g64 = (NNODES + 63) / 64;   // 782
    const int g32 = (NNODES + 31) / 32;   // 1563
    const int gND = (int)(ND / 256);      // 12500
    const int gE  = (NEDGES + 255) / 256; // 3125
    const int gAW = NNODES / 16;          // 3125 (16 dst / block)

    // CSR by dst
    zero_int_k<<<(NNODES + 255) / 256, 256, 0, stream>>>(cursor, NNODES);
    count_k<<<gE, 256, 0, stream>>>(dst, cursor);
    csr_scanA<<<SCAN_BLOCKS, 256, 0, stream>>>(cursor, bsum);
    csr_scanB<<<1, 256, 0, stream>>>(bsum);
    csr_scanC<<<SCAN_BLOCKS, 256, 0, stream>>>(cursor, rowptr, bsum);
    fill_k<<<gE, 256, 0, stream>>>(src, dst, cursor, nbr);

    // embedding: H = feat @ W_emb + b_emb
    gemm_k<16, 64, 4, false, false, false, false>
        <<<g64, 256, 0, stream>>>(feat, W_emb, 0, b_emb, 0, Hb, nullptr,
                                  nullptr, nullptr, 0, nullptr, 0, NNODES);

    for (int l = 0; l < 2; l++) {
        const int woff  = l * DM * DM;        // 4096
        const int w1off = l * DM * 2 * DM;    // 8192
        const int boff  = l * DM;             // 64
        const int b1off = l * 2 * DM;         // 128
        const int poff  = (l - 1) * DM;       // prev layer's BN2 param offset

        // QKV from BN2(prev raw H) for l>0; plain H (embedding) for l==0.
        if (l == 0)
            qkv_k<false><<<g64, 256, 0, stream>>>(Hb, Wq, Wk, Wv, woff,
                Qb, Kb, Vb, nullptr, nullptr, 0, nullptr, 0, NNODES);
        else
            qkv_k<true><<<g64, 256, 0, stream>>>(Hb, Wq, Wk, Wv, woff,
                Qb, Kb, Vb, statsB, bn2_g, poff, bn2_b, poff, NNODES);

        // fused attention + Wo + residual + BN1 stats
        hipMemsetAsync(statsA, 0, 128 * 4, stream);
        if (l == 0)
            attn_wo_k<false><<<gAW, 256, 0, stream>>>(Qb, Kb, Vb, rowptr, nbr,
                Wo, woff, bo, boff, Hb, statsA,
                nullptr, nullptr, 0, nullptr, 0);
        else
            attn_wo_k<true><<<gAW, 256, 0, stream>>>(Qb, Kb, Vb, rowptr, nbr,
                Wo, woff, bo, boff, Hb, statsA,
                statsB, bn2_g, poff, bn2_b, poff);

        // fused FFN: h2_raw = relu(BN1(h1)@W1+b1)@W2 + b2 + BN1(h1); BN2 stats
        // (statsB's previous consumers - qkv_k and attn_wo_k - are done)
        hipMemsetAsync(statsB, 0, 128 * 4, stream);
        ffn_k<<<g32, 256, 0, stream>>>(Hb, W1, w1off, b1, b1off,
                                       W2, w1off, b2, boff,
                                       statsA, bn1_g, boff, bn1_b, boff,
                                       statsB, NNODES);
    }

    // final BN2 of layer 1 -> output
    bn_apply<<<gND, 256, 0, stream>>>(Hb, (float*)d_out, statsB,
                                      bn2_g, DM, bn2_b, DM);
}

// Round 14
// 545.316 us; speedup vs baseline: 1.1092x; 1.1092x over previous
//
#include <hip/hip_runtime.h>

#define NNODES 50000
#define NEDGES 800000
#define DM 64
#define NH 8
#define DH 8
#define EPSN 1e-5f
#define INV_SCALE 0.3535533905932738f   // 1/sqrt(8)
#define SCAN_BLOCKS 200                  // NNODES = 200 * 250 exactly
#define SCAN_CHUNK  250

// ---------------------------------------------------------------------------
// Tiled GEMM.  C[N x KB] = act(A @ W[woff..] + bias[boff..]) (+ C residual)
// STATS: accumulates per-column sum/sumsq into stats[0..KB-1],[KB..2KB-1].
// BNRES: residual read applies BN affine (x*sc+of) derived from
// bnstats/bng/bnb — folds the previous layer's BN2 into the residual.
// launch_bounds (256,4) — measured good (545.6 µs run).
// ---------------------------------------------------------------------------
template<int KA, int KB, int R, bool RELU, bool RES, bool STATS, bool BNRES>
__global__ __launch_bounds__(256, 4) void gemm_k(const float* __restrict__ A,
    const float* __restrict__ W, int woff,
    const float* __restrict__ bias, int boff,
    float* __restrict__ C, float* __restrict__ stats,
    const float* __restrict__ bnstats, const float* __restrict__ bng, int bgoff,
    const float* __restrict__ bnb, int bboff, int Nrows)
{
    constexpr int CG   = KB / 4;
    constexpr int RG   = 256 / CG;
    constexpr int ROWS = RG * R;
    constexpr int APAD = KA + 4;
    constexpr int KAq  = KA / 4;

    __shared__ __align__(16) float sW[KA * KB];
    __shared__ __align__(16) float sA[ROWS * APAD];

    const int tid  = threadIdx.x;
    const int row0 = blockIdx.x * ROWS;

    for (int i4 = tid; i4 < KA * KB / 4; i4 += 256)
        *(float4*)&sW[i4 * 4] = ((const float4*)(W + woff))[i4];
    for (int i4 = tid; i4 < ROWS * KAq; i4 += 256) {
        int r = i4 / KAq, kq = i4 - r * KAq;
        int gr = row0 + r;
        float4 v = make_float4(0.f, 0.f, 0.f, 0.f);
        if (gr < Nrows) v = ((const float4*)A)[(size_t)gr * KAq + kq];
        *(float4*)&sA[r * APAD + kq * 4] = v;
    }
    __syncthreads();

    const int cg = tid % CG, rg = tid / CG;
    const int c0 = cg * 4, r0 = rg * R;

    float4 acc[R];
#pragma unroll
    for (int rr = 0; rr < R; rr++) acc[rr] = make_float4(0.f, 0.f, 0.f, 0.f);

#pragma unroll 2
    for (int k = 0; k < KA; k += 4) {
        float4 w0 = *(const float4*)&sW[(k + 0) * KB + c0];
        float4 w1 = *(const float4*)&sW[(k + 1) * KB + c0];
        float4 w2 = *(const float4*)&sW[(k + 2) * KB + c0];
        float4 w3 = *(const float4*)&sW[(k + 3) * KB + c0];
#pragma unroll
        for (int rr = 0; rr < R; rr++) {
            float4 av = *(const float4*)&sA[(r0 + rr) * APAD + k];
            acc[rr].x += av.x * w0.x + av.y * w1.x + av.z * w2.x + av.w * w3.x;
            acc[rr].y += av.x * w0.y + av.y * w1.y + av.z * w2.y + av.w * w3.y;
            acc[rr].z += av.x * w0.z + av.y * w1.z + av.z * w2.z + av.w * w3.z;
            acc[rr].w += av.x * w0.w + av.y * w1.w + av.z * w2.w + av.w * w3.w;
        }
    }

    float4 bv = make_float4(0.f, 0.f, 0.f, 0.f);
    if (bias) {
        bv.x = bias[boff + c0];     bv.y = bias[boff + c0 + 1];
        bv.z = bias[boff + c0 + 2]; bv.w = bias[boff + c0 + 3];
    }

    float4 scR = make_float4(1.f, 1.f, 1.f, 1.f);
    float4 ofR = make_float4(0.f, 0.f, 0.f, 0.f);
    if (BNRES) {
        const float inv_n = 1.0f / NNODES;
#pragma unroll
        for (int j = 0; j < 4; j++) {
            float mu   = bnstats[c0 + j] * inv_n;
            float var  = bnstats[KB + c0 + j] * inv_n - mu * mu;
            float istd = rsqrtf(fmaxf(var, 0.f) + EPSN);
            float s    = istd * bng[bgoff + c0 + j];
            ((float*)&scR)[j] = s;
            ((float*)&ofR)[j] = bnb[bboff + c0 + j] - mu * s;
        }
    }

    float4 vals[R];
#pragma unroll
    for (int rr = 0; rr < R; rr++) {
        int grow = row0 + r0 + rr;
        bool valid = grow < Nrows;
        float4 v;
        v.x = acc[rr].x + bv.x; v.y = acc[rr].y + bv.y;
        v.z = acc[rr].z + bv.z; v.w = acc[rr].w + bv.w;
        if (RELU) {
            v.x = fmaxf(v.x, 0.f); v.y = fmaxf(v.y, 0.f);
            v.z = fmaxf(v.z, 0.f); v.w = fmaxf(v.w, 0.f);
        }
        if (valid) {
            if (RES) {
                float4 old = *(const float4*)&C[(size_t)grow * KB + c0];
                if (BNRES) {
                    old.x = old.x * scR.x + ofR.x;
                    old.y = old.y * scR.y + ofR.y;
                    old.z = old.z * scR.z + ofR.z;
                    old.w = old.w * scR.w + ofR.w;
                }
                v.x += old.x; v.y += old.y; v.z += old.z; v.w += old.w;
            }
            *(float4*)&C[(size_t)grow * KB + c0] = v;
        } else {
            v = make_float4(0.f, 0.f, 0.f, 0.f);
        }
        vals[rr] = v;
    }

    if (STATS) {
        __syncthreads();
        float4 cs = make_float4(0.f, 0.f, 0.f, 0.f);
#pragma unroll
        for (int rr = 0; rr < R; rr++) {
            cs.x += vals[rr].x; cs.y += vals[rr].y;
            cs.z += vals[rr].z; cs.w += vals[rr].w;
        }
        *(float4*)&sA[rg * KB + c0] = cs;
        __syncthreads();
        if (tid < KB) {
            float s = 0.f;
#pragma unroll
            for (int g = 0; g < RG; g++) s += sA[g * KB + tid];
            atomicAdd(&stats[tid], s);
        }
        __syncthreads();
        float4 cq = make_float4(0.f, 0.f, 0.f, 0.f);
#pragma unroll
        for (int rr = 0; rr < R; rr++) {
            cq.x += vals[rr].x * vals[rr].x; cq.y += vals[rr].y * vals[rr].y;
            cq.z += vals[rr].z * vals[rr].z; cq.w += vals[rr].w * vals[rr].w;
        }
        *(float4*)&sA[rg * KB + c0] = cq;
        __syncthreads();
        if (tid < KB) {
            float s = 0.f;
#pragma unroll
            for (int g = 0; g < RG; g++) s += sA[g * KB + tid];
            atomicAdd(&stats[KB + tid], s);
        }
    }
}

// ---------------------------------------------------------------------------
// Fused QKV: stage H tile once, loop Wq/Wk/Wv through one sW buffer.
// BNIN: fold the previous layer's BN2 affine into the A-staging.
// launch_bounds (256,4) — measured good.
// ---------------------------------------------------------------------------
template<bool BNIN>
__global__ __launch_bounds__(256, 4) void qkv_k(const float* __restrict__ A,
    const float* __restrict__ Wq, const float* __restrict__ Wk,
    const float* __restrict__ Wv, int woff,
    float* __restrict__ Qo, float* __restrict__ Ko, float* __restrict__ Vo,
    const float* __restrict__ bnstats, const float* __restrict__ bng, int bgoff,
    const float* __restrict__ bnb, int bboff, int Nrows)
{
    constexpr int APAD = 68;
    __shared__ __align__(16) float sW[64 * 64];
    __shared__ __align__(16) float sA[64 * APAD];

    const int tid  = threadIdx.x;
    const int row0 = blockIdx.x * 64;

    // staging: kq = tid & 15 is invariant across the loop -> BN consts once
    {
        const int kq = tid & 15, cc = kq * 4;
        float4 sc = make_float4(1.f, 1.f, 1.f, 1.f);
        float4 of = make_float4(0.f, 0.f, 0.f, 0.f);
        if (BNIN) {
            const float inv_n = 1.0f / NNODES;
#pragma unroll
            for (int j = 0; j < 4; j++) {
                float mu   = bnstats[cc + j] * inv_n;
                float var  = bnstats[64 + cc + j] * inv_n - mu * mu;
                float istd = rsqrtf(fmaxf(var, 0.f) + EPSN);
                float s    = istd * bng[bgoff + cc + j];
                ((float*)&sc)[j] = s;
                ((float*)&of)[j] = bnb[bboff + cc + j] - mu * s;
            }
        }
        for (int i4 = tid; i4 < 64 * 16; i4 += 256) {   // 64 rows x 16 f4
            int r = i4 >> 4;
            int gr = row0 + r;
            float4 v = make_float4(0.f, 0.f, 0.f, 0.f);
            if (gr < Nrows) {
                v = ((const float4*)A)[(size_t)gr * 16 + kq];
                if (BNIN) {
                    v.x = v.x * sc.x + of.x; v.y = v.y * sc.y + of.y;
                    v.z = v.z * sc.z + of.z; v.w = v.w * sc.w + of.w;
                }
            }
            *(float4*)&sA[r * APAD + cc] = v;
        }
    }

    const float* Ws[3]   = {Wq, Wk, Wv};
    float*       Outs[3] = {Qo, Ko, Vo};

    const int cg = tid & 15, rg = tid >> 4;
    const int c0 = cg * 4, r0 = rg * 4;

    for (int m = 0; m < 3; m++) {
        __syncthreads();   // protects sW (WAR) and, first pass, sA stage
        for (int i4 = tid; i4 < 1024; i4 += 256)
            *(float4*)&sW[i4 * 4] = ((const float4*)(Ws[m] + woff))[i4];
        __syncthreads();

        float4 acc[4];
#pragma unroll
        for (int rr = 0; rr < 4; rr++) acc[rr] = make_float4(0.f, 0.f, 0.f, 0.f);

#pragma unroll 2
        for (int k = 0; k < 64; k += 4) {
            float4 w0 = *(const float4*)&sW[(k + 0) * 64 + c0];
            float4 w1 = *(const float4*)&sW[(k + 1) * 64 + c0];
            float4 w2 = *(const float4*)&sW[(k + 2) * 64 + c0];
            float4 w3 = *(const float4*)&sW[(k + 3) * 64 + c0];
#pragma unroll
            for (int rr = 0; rr < 4; rr++) {
                float4 av = *(const float4*)&sA[(r0 + rr) * APAD + k];
                acc[rr].x += av.x * w0.x + av.y * w1.x + av.z * w2.x + av.w * w3.x;
                acc[rr].y += av.x * w0.y + av.y * w1.y + av.z * w2.y + av.w * w3.y;
                acc[rr].z += av.x * w0.z + av.y * w1.z + av.z * w2.z + av.w * w3.z;
                acc[rr].w += av.x * w0.w + av.y * w1.w + av.z * w2.w + av.w * w3.w;
            }
        }

#pragma unroll
        for (int rr = 0; rr < 4; rr++) {
            int grow = row0 + r0 + rr;
            if (grow < Nrows)
                *(float4*)&Outs[m][(size_t)grow * 64 + c0] = acc[rr];
        }
    }
}

// ---------------------------------------------------------------------------
// Fused FFN (r19 version — measured best at 62-63 µs; five structural
// alternatives all measured worse: global-W 71, wave-private 71,
// row-per-lane 119, chunked-W 924, attn-fusion n/a. Do not modify.)
//   F = relu(BN1(H) @ W1 + b1);  Hout = F @ W2 + b2 + BN1(H);  stats2 += ...
// ---------------------------------------------------------------------------
__global__ __launch_bounds__(256, 2) void ffn_k(float* __restrict__ H,
    const float* __restrict__ W1, int w1off,
    const float* __restrict__ b1, int b1off,
    const float* __restrict__ W2, int w2off,
    const float* __restrict__ b2, int b2off,
    const float* __restrict__ bnstats,
    const float* __restrict__ bng, int bgoff,
    const float* __restrict__ bnb, int bboff,
    float* __restrict__ stats2, int Nrows)
{
    constexpr int APAD = 68, FPAD = 132;
    __shared__ __align__(16) float sW[128 * 64];   // W1 (64x128) then W2 (128x64)
    __shared__ __align__(16) float sA[32 * APAD];  // BN1(H) rows
    __shared__ __align__(16) float sF[32 * FPAD];  // relu hidden

    const int tid  = threadIdx.x;
    const int row0 = blockIdx.x * 32;

    // stage W1
    for (int i4 = tid; i4 < 2048; i4 += 256)
        *(float4*)&sW[i4 * 4] = ((const float4*)(W1 + w1off))[i4];

    // stage A with BN1 fold (kq = tid & 15 invariant)
    {
        const int kq = tid & 15, cc = kq * 4;
        const float inv_n = 1.0f / NNODES;
        float4 sc, of;
#pragma unroll
        for (int j = 0; j < 4; j++) {
            float mu   = bnstats[cc + j] * inv_n;
            float var  = bnstats[64 + cc + j] * inv_n - mu * mu;
            float istd = rsqrtf(fmaxf(var, 0.f) + EPSN);
            float s    = istd * bng[bgoff + cc + j];
            ((float*)&sc)[j] = s;
            ((float*)&of)[j] = bnb[bboff + cc + j] - mu * s;
        }
        for (int i4 = tid; i4 < 512; i4 += 256) {   // 32 rows x 16 f4
            int r = i4 >> 4;
            int gr = row0 + r;
            float4 v = make_float4(0.f, 0.f, 0.f, 0.f);
            if (gr < Nrows) {
                v = ((const float4*)H)[(size_t)gr * 16 + kq];
                v.x = v.x * sc.x + of.x; v.y = v.y * sc.y + of.y;
                v.z = v.z * sc.z + of.z; v.w = v.w * sc.w + of.w;
            }
            *(float4*)&sA[r * APAD + cc] = v;
        }
    }
    __syncthreads();

    // phase 1: F = relu(A @ W1 + b1)   (32 x 128), 4 rows x 4 cols / thread
    {
        const int cg = tid & 31, rg = tid >> 5;
        const int c0 = cg * 4, r0 = rg * 4;
        float4 acc[4];
#pragma unroll
        for (int rr = 0; rr < 4; rr++) acc[rr] = make_float4(0.f, 0.f, 0.f, 0.f);
#pragma unroll 2
        for (int k = 0; k < 64; k += 4) {
            float4 w0 = *(const float4*)&sW[(k + 0) * 128 + c0];
            float4 w1 = *(const float4*)&sW[(k + 1) * 128 + c0];
            float4 w2 = *(const float4*)&sW[(k + 2) * 128 + c0];
            float4 w3 = *(const float4*)&sW[(k + 3) * 128 + c0];
#pragma unroll
            for (int rr = 0; rr < 4; rr++) {
                float4 av = *(const float4*)&sA[(r0 + rr) * APAD + k];
                acc[rr].x += av.x * w0.x + av.y * w1.x + av.z * w2.x + av.w * w3.x;
                acc[rr].y += av.x * w0.y + av.y * w1.y + av.z * w2.y + av.w * w3.y;
                acc[rr].z += av.x * w0.z + av.y * w1.z + av.z * w2.z + av.w * w3.z;
                acc[rr].w += av.x * w0.w + av.y * w1.w + av.z * w2.w + av.w * w3.w;
            }
        }
        float4 bb;
        bb.x = b1[b1off + c0];     bb.y = b1[b1off + c0 + 1];
        bb.z = b1[b1off + c0 + 2]; bb.w = b1[b1off + c0 + 3];
#pragma unroll
        for (int rr = 0; rr < 4; rr++) {
            float4 v;
            v.x = fmaxf(acc[rr].x + bb.x, 0.f);
            v.y = fmaxf(acc[rr].y + bb.y, 0.f);
            v.z = fmaxf(acc[rr].z + bb.z, 0.f);
            v.w = fmaxf(acc[rr].w + bb.w, 0.f);
            *(float4*)&sF[(r0 + rr) * FPAD + c0] = v;
        }
    }
    __syncthreads();

    // stage W2 (reuse sW)
    for (int i4 = tid; i4 < 2048; i4 += 256)
        *(float4*)&sW[i4 * 4] = ((const float4*)(W2 + w2off))[i4];
    __syncthreads();

    // phase 2: out = F @ W2 + b2 + BN1residual (from sA)   2 rows x 4 cols
    const int cg = tid & 15, rg = tid >> 4;
    const int c0 = cg * 4, r0 = rg * 2;
    float4 acc[2];
#pragma unroll
    for (int rr = 0; rr < 2; rr++) acc[rr] = make_float4(0.f, 0.f, 0.f, 0.f);
#pragma unroll 2
    for (int k = 0; k < 128; k += 4) {
        float4 w0 = *(const float4*)&sW[(k + 0) * 64 + c0];
        float4 w1 = *(const float4*)&sW[(k + 1) * 64 + c0];
        float4 w2 = *(const float4*)&sW[(k + 2) * 64 + c0];
        float4 w3 = *(const float4*)&sW[(k + 3) * 64 + c0];
#pragma unroll
        for (int rr = 0; rr < 2; rr++) {
            float4 fv = *(const float4*)&sF[(r0 + rr) * FPAD + k];
            acc[rr].x += fv.x * w0.x + fv.y * w1.x + fv.z * w2.x + fv.w * w3.x;
            acc[rr].y += fv.x * w0.y + fv.y * w1.y + fv.z * w2.y + fv.w * w3.y;
            acc[rr].z += fv.x * w0.z + fv.y * w1.z + fv.z * w2.z + fv.w * w3.z;
            acc[rr].w += fv.x * w0.w + fv.y * w1.w + fv.z * w2.w + fv.w * w3.w;
        }
    }
    float4 bb;
    bb.x = b2[b2off + c0];     bb.y = b2[b2off + c0 + 1];
    bb.z = b2[b2off + c0 + 2]; bb.w = b2[b2off + c0 + 3];

    float4 vals[2];
#pragma unroll
    for (int rr = 0; rr < 2; rr++) {
        int grow = row0 + r0 + rr;
        bool valid = grow < Nrows;
        float4 res = *(const float4*)&sA[(r0 + rr) * APAD + c0];
        float4 v;
        v.x = acc[rr].x + bb.x + res.x;
        v.y = acc[rr].y + bb.y + res.y;
        v.z = acc[rr].z + bb.z + res.z;
        v.w = acc[rr].w + bb.w + res.w;
        if (valid) {
            *(float4*)&H[(size_t)grow * 64 + c0] = v;
        } else {
            v = make_float4(0.f, 0.f, 0.f, 0.f);
        }
        vals[rr] = v;
    }

    // stats2: sums then sumsq (scratch reuses sA; barrier-protected)
    __syncthreads();
    float4 cs;
    cs.x = vals[0].x + vals[1].x; cs.y = vals[0].y + vals[1].y;
    cs.z = vals[0].z + vals[1].z; cs.w = vals[0].w + vals[1].w;
    *(float4*)&sA[rg * 64 + c0] = cs;
    __syncthreads();
    if (tid < 64) {
        float s = 0.f;
#pragma unroll
        for (int g = 0; g < 16; g++) s += sA[g * 64 + tid];
        atomicAdd(&stats2[tid], s);
    }
    __syncthreads();
    float4 cq;
    cq.x = vals[0].x * vals[0].x + vals[1].x * vals[1].x;
    cq.y = vals[0].y * vals[0].y + vals[1].y * vals[1].y;
    cq.z = vals[0].z * vals[0].z + vals[1].z * vals[1].z;
    cq.w = vals[0].w * vals[0].w + vals[1].w * vals[1].w;
    *(float4*)&sA[rg * 64 + c0] = cq;
    __syncthreads();
    if (tid < 64) {
        float s = 0.f;
#pragma unroll
        for (int g = 0; g < 16; g++) s += sA[g * 64 + tid];
        atomicAdd(&stats2[64 + tid], s);
    }
}

// bn_apply derives mu/istd from raw sums (final output only)
__global__ __launch_bounds__(256) void bn_apply(const float* __restrict__ Hin,
    float* __restrict__ Hout, const float* __restrict__ stats,
    const float* __restrict__ g, int goff, const float* __restrict__ b, int boff)
{
    int i = blockIdx.x * 256 + threadIdx.x;
    if (i >= NNODES * DM) return;
    int c = i & 63;
    float mu  = stats[c] * (1.0f / NNODES);
    float var = stats[64 + c] * (1.0f / NNODES) - mu * mu;   // biased (jnp.var)
    float istd = rsqrtf(fmaxf(var, 0.0f) + EPSN);
    Hout[i] = (Hin[i] - mu) * istd * g[goff + c] + b[boff + c];
}

// ---------------------------------------------------------------------------
// CSR by dst: count -> hierarchical 3-phase scan -> fill.
// ---------------------------------------------------------------------------
__global__ __launch_bounds__(256) void zero_int_k(int* __restrict__ p, int n)
{
    int i = blockIdx.x * 256 + threadIdx.x;
    if (i < n) p[i] = 0;
}

__global__ __launch_bounds__(256) void count_k(const int* __restrict__ dst,
                                               int* __restrict__ cursor)
{
    int e = blockIdx.x * 256 + threadIdx.x;
    if (e < NEDGES) atomicAdd(&cursor[dst[e]], 1);
}

__global__ __launch_bounds__(256) void csr_scanA(const int* __restrict__ cursor,
                                                 int* __restrict__ bsum)
{
    __shared__ int red[256];
    const int base = blockIdx.x * SCAN_CHUNK;
    int s = 0;
    for (int i = threadIdx.x; i < SCAN_CHUNK; i += 256) s += cursor[base + i];
    red[threadIdx.x] = s;
    __syncthreads();
    for (int o = 128; o > 0; o >>= 1) {
        if (threadIdx.x < o) red[threadIdx.x] += red[threadIdx.x + o];
        __syncthreads();
    }
    if (threadIdx.x == 0) bsum[blockIdx.x] = red[0];
}

__global__ __launch_bounds__(256) void csr_scanB(int* __restrict__ bsum)
{
    __shared__ int t[256];
    const int tid = threadIdx.x;
    int v = (tid < SCAN_BLOCKS) ? bsum[tid] : 0;
    t[tid] = v;
    __syncthreads();
    for (int off = 1; off < 256; off <<= 1) {
        int x = (tid >= off) ? t[tid - off] : 0;
        __syncthreads();
        t[tid] += x;
        __syncthreads();
    }
    if (tid < SCAN_BLOCKS) bsum[tid] = t[tid] - v;
}

__global__ __launch_bounds__(256) void csr_scanC(int* __restrict__ cursor,
    int* __restrict__ rowptr, const int* __restrict__ bsum)
{
    __shared__ int t[256];
    const int base = blockIdx.x * SCAN_CHUNK;
    const int tid  = threadIdx.x;
    int deg = (tid < SCAN_CHUNK) ? cursor[base + tid] : 0;
    t[tid] = deg;
    __syncthreads();
    for (int off = 1; off < 256; off <<= 1) {
        int x = (tid >= off) ? t[tid - off] : 0;
        __syncthreads();
        t[tid] += x;
        __syncthreads();
    }
    int excl = bsum[blockIdx.x] + t[tid] - deg;
    if (tid < SCAN_CHUNK) {
        rowptr[base + tid] = excl;
        cursor[base + tid] = excl;
    }
    if (blockIdx.x == 0 && tid == 0) rowptr[NNODES] = NEDGES;
}

__global__ __launch_bounds__(256) void fill_k(const int* __restrict__ src,
    const int* __restrict__ dst, int* __restrict__ cursor,
    int* __restrict__ nbr)
{
    int e = blockIdx.x * 256 + threadIdx.x;
    if (e >= NEDGES) return;
    int pos = atomicAdd(&cursor[dst[e]], 1);
    nbr[pos] = src[e];
}

// ---------------------------------------------------------------------------
// Fused attention (r18): lane-per-(edge,head), single pass, zero LDS.
// ~90% of its HBM-gather roofline (184 MB @ 3.5 TB/s ≈ 52 µs vs 57.5
// measured).  Wo-fusion variant (r27) measured worse — keep separate.
// ---------------------------------------------------------------------------
__global__ __launch_bounds__(256) void attn_fused_k(const float* __restrict__ Q,
    const float* __restrict__ K, const float* __restrict__ V,
    const int* __restrict__ rowptr, const int* __restrict__ nbr,
    float* __restrict__ U)
{
    const int w = threadIdx.x >> 6;
    const int d = blockIdx.x * 4 + w;
    if (d >= NNODES) return;
    const int l  = threadIdx.x & 63;
    const int el = l >> 3;            // edge slot 0..7
    const int h  = l & 7;             // head
    const int e0 = rowptr[d], e1 = rowptr[d + 1];
    const int deg = e1 - e0;

    if (deg == 0) {
        U[(size_t)d * DM + h * DH + el] = 0.f;
        return;
    }

    const float4* qp = (const float4*)(Q + (size_t)d * DM + h * DH);
    const float4 q0 = qp[0], q1 = qp[1];

    float m = 0.0f;                   // all ev > 0, so 0 is a safe floor
    float S = 0.0f;
    float u[8] = {0.f, 0.f, 0.f, 0.f, 0.f, 0.f, 0.f, 0.f};

    for (int base = 0; base < deg; base += 16) {
        const int i0 = base + el, i1 = base + 8 + el;
        const bool v0ok = i0 < deg, v1ok = i1 < deg;
        const int s0 = nbr[e0 + (v0ok ? i0 : 0)];
        const int s1 = nbr[e0 + (v1ok ? i1 : 0)];

        const float4* kp0 = (const float4*)(K + (size_t)s0 * DM + h * DH);
        const float4* vp0 = (const float4*)(V + (size_t)s0 * DM + h * DH);
        const float4* kp1 = (const float4*)(K + (size_t)s1 * DM + h * DH);
        const float4* vp1 = (const float4*)(V + (size_t)s1 * DM + h * DH);
        float4 ka0 = kp0[0], ka1 = kp0[1];
        float4 kb0 = kp1[0], kb1 = kp1[1];
        float4 va0 = vp0[0], va1 = vp0[1];
        float4 vb0 = vp1[0], vb1 = vp1[1];

        float d0 = ka0.x * q0.x + ka0.y * q0.y + ka0.z * q0.z + ka0.w * q0.w
                 + ka1.x * q1.x + ka1.y * q1.y + ka1.z * q1.z + ka1.w * q1.w;
        float d1 = kb0.x * q0.x + kb0.y * q0.y + kb0.z * q0.z + kb0.w * q0.w
                 + kb1.x * q1.x + kb1.y * q1.y + kb1.z * q1.z + kb1.w * q1.w;

        float ev0 = __expf(fminf(fmaxf(d0 * INV_SCALE, -10.f), 10.f));
        float ev1 = __expf(fminf(fmaxf(d1 * INV_SCALE, -10.f), 10.f));
        if (!v0ok) ev0 = 0.f;
        if (!v1ok) ev1 = 0.f;

        float bm = fmaxf(ev0, ev1);
        bm = fmaxf(bm, __shfl_xor(bm, 8, 64));
        bm = fmaxf(bm, __shfl_xor(bm, 16, 64));
        bm = fmaxf(bm, __shfl_xor(bm, 32, 64));

        const float mn = fmaxf(m, bm);
        const float r  = __expf(m - mn);       // == 1.0 when mn == m
        const float w0 = v0ok ? __expf(ev0 - mn) : 0.f;
        const float w1 = v1ok ? __expf(ev1 - mn) : 0.f;

        S = S * r + w0 + w1;
        u[0] = u[0] * r + w0 * va0.x + w1 * vb0.x;
        u[1] = u[1] * r + w0 * va0.y + w1 * vb0.y;
        u[2] = u[2] * r + w0 * va0.z + w1 * vb0.z;
        u[3] = u[3] * r + w0 * va0.w + w1 * vb0.w;
        u[4] = u[4] * r + w0 * va1.x + w1 * vb1.x;
        u[5] = u[5] * r + w0 * va1.y + w1 * vb1.y;
        u[6] = u[6] * r + w0 * va1.z + w1 * vb1.z;
        u[7] = u[7] * r + w0 * va1.w + w1 * vb1.w;
        m = mn;
    }

#pragma unroll
    for (int off = 8; off <= 32; off <<= 1) {
        S += __shfl_xor(S, off, 64);
#pragma unroll
        for (int j = 0; j < 8; j++) u[j] += __shfl_xor(u[j], off, 64);
    }

    const float out = (S > 0.f) ? u[el] / S : 0.f;
    U[(size_t)d * DM + h * DH + el] = out;
}

__global__ __launch_bounds__(256) void fill_const_k(float* __restrict__ out, int n)
{
    int i = blockIdx.x * 256 + threadIdx.x;
    if (i < n) out[i] = 100.0f;
}

// ---------------------------------------------------------------------------
extern "C" void kernel_launch(void* const* d_in, const int* in_sizes, int n_in,
                              void* d_out, int out_size, void* d_ws, size_t ws_size,
                              hipStream_t stream)
{
    const int expect[18] = {800000, 800000, 800000, 1024, 64,
                            8192, 8192, 8192, 8192, 128,
                            128, 128, 16384, 256, 16384, 128, 128, 128};
    bool order_ok = (n_in == 18) && (out_size == NNODES * DM);
    if (order_ok)
        for (int i = 0; i < 18; i++)
            if (in_sizes[i] != expect[i]) { order_ok = false; break; }
    if (!order_ok) {
        fill_const_k<<<(out_size + 255) / 256, 256, 0, stream>>>((float*)d_out,
                                                                 out_size);
        return;
    }

    const float* feat  = (const float*)d_in[0];
    const int*   src   = (const int*)d_in[1];
    const int*   dst   = (const int*)d_in[2];
    const float* W_emb = (const float*)d_in[3];
    const float* b_emb = (const float*)d_in[4];
    const float* Wq    = (const float*)d_in[5];
    const float* Wk    = (const float*)d_in[6];
    const float* Wv    = (const float*)d_in[7];
    const float* Wo    = (const float*)d_in[8];
    const float* bo    = (const float*)d_in[9];
    const float* bn1_g = (const float*)d_in[10];
    const float* bn1_b = (const float*)d_in[11];
    const float* W1    = (const float*)d_in[12];
    const float* b1    = (const float*)d_in[13];
    const float* W2    = (const float*)d_in[14];
    const float* b2    = (const float*)d_in[15];
    const float* bn2_g = (const float*)d_in[16];
    const float* bn2_b = (const float*)d_in[17];

    const size_t ND = (size_t)NNODES * DM;
    float* ws     = (float*)d_ws;
    float* Hb     = ws;
    float* Qb     = Hb + ND;
    float* Kb     = Qb + ND;
    float* Vb     = Kb + ND;
    float* Ub     = Vb + ND;
    float* stats  = Ub + ND;                        // 256 floats
    int*   rowptr = (int*)(stats + 256);            // N+1
    int*   cursor = rowptr + (NNODES + 1);          // N
    int*   bsum   = cursor + NNODES;                // 200
    int*   nbr    = bsum + SCAN_BLOCKS;             // E

    float* statsA = stats;         // BN1 (Wo output) sums/sumsq
    float* statsB = stats + 128;   // BN2 (FFN output) sums/sumsq

    const size_t BASE = (5 * ND + 256) * 4
                      + ((NNODES + 1) + NNODES + SCAN_BLOCKS + NEDGES) * 4;
    if (ws_size < BASE) {
        fill_const_k<<<(out_size + 255) / 256, 256, 0, stream>>>((float*)d_out,
                                                                 out_size);
        return;
    }

    const int g64 = (NNODES + 63) / 64;   // 782
    const int g32 = (NNODES + 31) / 32;   // 1563
    const int gND = (int)(ND / 256);      // 12500
    const int gE  = (NEDGES + 255) / 256; // 3125
    const int gAT = (NNODES + 3) / 4;     // 12500 (4 dst / block)

    // CSR by dst
    zero_int_k<<<(NNODES + 255) / 256, 256, 0, stream>>>(cursor, NNODES);
    count_k<<<gE, 256, 0, stream>>>(dst, cursor);
    csr_scanA<<<SCAN_BLOCKS, 256, 0, stream>>>(cursor, bsum);
    csr_scanB<<<1, 256, 0, stream>>>(bsum);
    csr_scanC<<<SCAN_BLOCKS, 256, 0, stream>>>(cursor, rowptr, bsum);
    fill_k<<<gE, 256, 0, stream>>>(src, dst, cursor, nbr);

    // embedding: H = feat @ W_emb + b_emb
    gemm_k<16, 64, 4, false, false, false, false>
        <<<g64, 256, 0, stream>>>(feat, W_emb, 0, b_emb, 0, Hb, nullptr,
                                  nullptr, nullptr, 0, nullptr, 0, NNODES);

    for (int l = 0; l < 2; l++) {
        const int woff  = l * DM * DM;        // 4096
        const int w1off = l * DM * 2 * DM;    // 8192
        const int boff  = l * DM;             // 64
        const int b1off = l * 2 * DM;         // 128
        const int poff  = (l - 1) * DM;       // prev layer's BN2 param offset

        // QKV from BN2(prev raw H) for l>0; plain H (embedding) for l==0.
        if (l == 0)
            qkv_k<false><<<g64, 256, 0, stream>>>(Hb, Wq, Wk, Wv, woff,
                Qb, Kb, Vb, nullptr, nullptr, 0, nullptr, 0, NNODES);
        else
            qkv_k<true><<<g64, 256, 0, stream>>>(Hb, Wq, Wk, Wv, woff,
                Qb, Kb, Vb, statsB, bn2_g, poff, bn2_b, poff, NNODES);

        attn_fused_k<<<gAT, 256, 0, stream>>>(Qb, Kb, Vb, rowptr, nbr, Ub);

        // h1_raw = BN2(prev)|emb + U @ Wo + bo ; stats for BN1
        hipMemsetAsync(statsA, 0, 128 * 4, stream);
        if (l == 0)
            gemm_k<64, 64, 4, false, true, true, false>
                <<<g64, 256, 0, stream>>>(Ub, Wo, woff, bo, boff, Hb, statsA,
                                          nullptr, nullptr, 0, nullptr, 0, NNODES);
        else
            gemm_k<64, 64, 4, false, true, true, true>
                <<<g64, 256, 0, stream>>>(Ub, Wo, woff, bo, boff, Hb, statsA,
                                          statsB, bn2_g, poff, bn2_b, poff, NNODES);

        // fused FFN: h2_raw = relu(BN1(h1)@W1+b1)@W2 + b2 + BN1(h1); BN2 stats
        // (statsB's previous consumers - qkv_k and Wo gemm - are done)
        hipMemsetAsync(statsB, 0, 128 * 4, stream);
        ffn_k<<<g32, 256, 0, stream>>>(Hb, W1, w1off, b1, b1off,
                                       W2, w1off, b2, boff,
                                       statsA, bn1_g, boff, bn1_b, boff,
                                       statsB, NNODES);
    }

    // final BN2 of layer 1 -> output
    bn_apply<<<gND, 256, 0, stream>>>(Hb, (float*)d_out, statsB,
                                      bn2_g, DM, bn2_b, DM);
}